// Round 1
// baseline (3497.521 us; speedup 1.0000x reference)
//
#include <hip/hip_runtime.h>
#include <math.h>

#define D_MODEL 2048
#define NUM_HEADS 16
#define D_K 128
#define BATCH 2
#define SEQ 2048

// ======================= GEMM: C[M][N] = A[M][K] @ B[N][K]^T =======================
// 128x128 tile, BK=16, 256 threads, 8x8 micro-tile per thread, fp32.
#define BM 128
#define BN 128
#define BKK 16

__global__ __launch_bounds__(256) void gemm_bt_kernel(
    const float* __restrict__ A, const float* __restrict__ B,
    float* __restrict__ C, int M, int N, int K)
{
    __shared__ float As[BKK][BM];   // transposed: As[k][m]
    __shared__ float Bs[BKK][BN];   // transposed: Bs[k][n]

    const int t   = threadIdx.x;
    const int tx  = t & 15;
    const int ty  = t >> 4;
    const int row0 = blockIdx.y * BM;
    const int col0 = blockIdx.x * BN;

    float acc[8][8];
#pragma unroll
    for (int i = 0; i < 8; i++)
#pragma unroll
        for (int j = 0; j < 8; j++) acc[i][j] = 0.f;

    for (int k0 = 0; k0 < K; k0 += BKK) {
        // stage A and B tiles into LDS (transposed). 512 float4 each / 256 threads.
#pragma unroll
        for (int f = t; f < BM * BKK / 4; f += 256) {
            const int r  = f >> 2;            // row within tile (128 rows, 4 f4/row)
            const int c4 = (f & 3) << 2;      // k-offset within tile
            const float4 av = *reinterpret_cast<const float4*>(
                &A[(size_t)(row0 + r) * K + k0 + c4]);
            As[c4 + 0][r] = av.x; As[c4 + 1][r] = av.y;
            As[c4 + 2][r] = av.z; As[c4 + 3][r] = av.w;
            const float4 bv = *reinterpret_cast<const float4*>(
                &B[(size_t)(col0 + r) * K + k0 + c4]);
            Bs[c4 + 0][r] = bv.x; Bs[c4 + 1][r] = bv.y;
            Bs[c4 + 2][r] = bv.z; Bs[c4 + 3][r] = bv.w;
        }
        __syncthreads();

#pragma unroll
        for (int kk = 0; kk < BKK; kk++) {
            float a[8], b[8];
            *reinterpret_cast<float4*>(&a[0]) = *reinterpret_cast<const float4*>(&As[kk][ty * 8]);
            *reinterpret_cast<float4*>(&a[4]) = *reinterpret_cast<const float4*>(&As[kk][ty * 8 + 4]);
            *reinterpret_cast<float4*>(&b[0]) = *reinterpret_cast<const float4*>(&Bs[kk][tx * 8]);
            *reinterpret_cast<float4*>(&b[4]) = *reinterpret_cast<const float4*>(&Bs[kk][tx * 8 + 4]);
#pragma unroll
            for (int i = 0; i < 8; i++)
#pragma unroll
                for (int j = 0; j < 8; j++)
                    acc[i][j] = fmaf(a[i], b[j], acc[i][j]);
        }
        __syncthreads();
    }

#pragma unroll
    for (int i = 0; i < 8; i++) {
        const size_t off = (size_t)(row0 + ty * 8 + i) * N + col0 + tx * 8;
        float4 v0 = make_float4(acc[i][0], acc[i][1], acc[i][2], acc[i][3]);
        float4 v1 = make_float4(acc[i][4], acc[i][5], acc[i][6], acc[i][7]);
        *reinterpret_cast<float4*>(&C[off])     = v0;
        *reinterpret_cast<float4*>(&C[off + 4]) = v1;
    }
}

// ======================= RoPE (in-place on q and k of qkv) =======================
// One thread per rotation pair. Angle in double for accuracy vs fp32 reference.
__global__ __launch_bounds__(256) void rope_kernel(
    float* __restrict__ qkv, const int* __restrict__ pos)
{
    const int idx = blockIdx.x * 256 + threadIdx.x;  // B*SEQ*2*16*64 = 8388608
    const int i  = idx & 63;            // pair index within head (half = 64)
    const int h  = (idx >> 6) & 15;     // head
    const int qk = (idx >> 10) & 1;     // 0 = q, 1 = k
    const int tt = (idx >> 11) & (SEQ - 1);
    const int b  = idx >> 22;

    const double inv_freq = exp(-log(10000.0) * (double)i / 64.0);
    const double ang = (double)pos[tt] * inv_freq;
    const float s = (float)sin(ang);
    const float c = (float)cos(ang);

    const size_t base = ((size_t)(b * SEQ + tt)) * (3 * D_MODEL) + qk * D_MODEL + h * D_K + 2 * i;
    const float e = qkv[base];
    const float o = qkv[base + 1];
    qkv[base]     = e * c - o * s;
    qkv[base + 1] = e * s + o * c;
}

// ======================= Causal flash attention (fp32) =======================
// Block: 256 threads; one (b,h) x 32-query-row tile; iterate 32-row KV tiles.
#define TQ 32
#define TKV 32
#define LDP 132   // padded LDS row (132 floats = 528 B, float4-aligned, breaks 32-way bank conflict)

__global__ __launch_bounds__(256) void attn_kernel(
    const float* __restrict__ qkv, float* __restrict__ outp)
{
    __shared__ float Qs[TQ][LDP];
    __shared__ float Ks[TKV][LDP];
    __shared__ float Vs[TKV][LDP];
    __shared__ float Ss[TQ][TKV + 1];
    __shared__ float mrow[TQ], lrow[TQ], arow[TQ];

    const int t  = threadIdx.x;
    const int bh = blockIdx.y;
    const int b  = bh >> 4;
    const int h  = bh & 15;
    const int q0 = blockIdx.x * TQ;
    const float scale = 0.08838834764831845f;   // 1/sqrt(128)

    // stage Q tile (pre-scaled)
    for (int f = t; f < TQ * D_K / 4; f += 256) {
        const int r = f >> 5;
        const int c = (f & 31) << 2;
        const float4 v = *reinterpret_cast<const float4*>(
            &qkv[((size_t)(b * SEQ + q0 + r)) * (3 * D_MODEL) + h * D_K + c]);
        Qs[r][c]     = v.x * scale;
        Qs[r][c + 1] = v.y * scale;
        Qs[r][c + 2] = v.z * scale;
        Qs[r][c + 3] = v.w * scale;
    }
    if (t < TQ) { mrow[t] = -INFINITY; lrow[t] = 0.f; }

    const int rS  = t & 31;           // score row
    const int cS0 = (t >> 5) << 2;    // score col base (4 cols per thread)
    const int rowA = t >> 3;          // accum row
    const int d0   = (t & 7) << 4;    // accum col base (16 cols per thread)

    float acc[16];
#pragma unroll
    for (int i = 0; i < 16; i++) acc[i] = 0.f;

    __syncthreads();

    for (int kv0 = 0; kv0 < q0 + TQ; kv0 += TKV) {
        // stage K and V tiles
        for (int f = t; f < TKV * D_K / 4; f += 256) {
            const int r = f >> 5;
            const int c = (f & 31) << 2;
            const size_t base = ((size_t)(b * SEQ + kv0 + r)) * (3 * D_MODEL) + h * D_K + c;
            const float4 k4 = *reinterpret_cast<const float4*>(&qkv[base + D_MODEL]);
            Ks[r][c] = k4.x; Ks[r][c + 1] = k4.y; Ks[r][c + 2] = k4.z; Ks[r][c + 3] = k4.w;
            const float4 v4 = *reinterpret_cast<const float4*>(&qkv[base + 2 * D_MODEL]);
            Vs[r][c] = v4.x; Vs[r][c + 1] = v4.y; Vs[r][c + 2] = v4.z; Vs[r][c + 3] = v4.w;
        }
        __syncthreads();

        // scores: each thread computes S[rS][cS0..cS0+3]
        float s[4] = {0.f, 0.f, 0.f, 0.f};
#pragma unroll
        for (int k = 0; k < D_K; k += 4) {
            const float4 q4 = *reinterpret_cast<const float4*>(&Qs[rS][k]);
#pragma unroll
            for (int j = 0; j < 4; j++) {
                const float4 k4 = *reinterpret_cast<const float4*>(&Ks[cS0 + j][k]);
                s[j] += q4.x * k4.x + q4.y * k4.y + q4.z * k4.z + q4.w * k4.w;
            }
        }
        const int qg = q0 + rS;
#pragma unroll
        for (int j = 0; j < 4; j++) {
            if (kv0 + cS0 + j > qg) s[j] = -1e30f;
            Ss[rS][cS0 + j] = s[j];
        }
        __syncthreads();

        // online softmax update, one thread per row
        if (t < TQ) {
            const float m_old = mrow[t];
            float mt = m_old;
#pragma unroll
            for (int c = 0; c < TKV; c++) mt = fmaxf(mt, Ss[t][c]);
            const float al = __expf(m_old - mt);
            float ls = 0.f;
#pragma unroll
            for (int c = 0; c < TKV; c++) {
                const float p = __expf(Ss[t][c] - mt);
                Ss[t][c] = p;
                ls += p;
            }
            mrow[t] = mt;
            lrow[t] = lrow[t] * al + ls;
            arow[t] = al;
        }
        __syncthreads();

        // rescale + accumulate P@V: thread owns (rowA, d0..d0+15)
        const float al = arow[rowA];
#pragma unroll
        for (int i = 0; i < 16; i++) acc[i] *= al;
#pragma unroll
        for (int c = 0; c < TKV; c++) {
            const float p = Ss[rowA][c];
#pragma unroll
            for (int i4 = 0; i4 < 4; i4++) {
                const float4 v4 = *reinterpret_cast<const float4*>(&Vs[c][d0 + i4 * 4]);
                acc[i4 * 4 + 0] = fmaf(p, v4.x, acc[i4 * 4 + 0]);
                acc[i4 * 4 + 1] = fmaf(p, v4.y, acc[i4 * 4 + 1]);
                acc[i4 * 4 + 2] = fmaf(p, v4.z, acc[i4 * 4 + 2]);
                acc[i4 * 4 + 3] = fmaf(p, v4.w, acc[i4 * 4 + 3]);
            }
        }
        __syncthreads();   // protect Ks/Vs/Ss before next tile's staging
    }

    // epilogue: O = acc / l, write to (B, T, H*D) layout
    const float linv = 1.f / lrow[rowA];
    const size_t off = ((size_t)(b * SEQ + q0 + rowA)) * D_MODEL + h * D_K + d0;
#pragma unroll
    for (int i4 = 0; i4 < 4; i4++) {
        float4 o4 = make_float4(acc[i4 * 4 + 0] * linv, acc[i4 * 4 + 1] * linv,
                                acc[i4 * 4 + 2] * linv, acc[i4 * 4 + 3] * linv);
        *reinterpret_cast<float4*>(&outp[off + i4 * 4]) = o4;
    }
}

// ======================= launch =======================
extern "C" void kernel_launch(void* const* d_in, const int* in_sizes, int n_in,
                              void* d_out, int out_size, void* d_ws, size_t ws_size,
                              hipStream_t stream)
{
    const float* x    = (const float*)d_in[0];
    const int*   pos  = (const int*)d_in[1];
    const float* Wqkv = (const float*)d_in[2];
    const float* Wo   = (const float*)d_in[3];
    float* out = (float*)d_out;

    // workspace: qkv (B*T*6144 f32 = 100.7 MB) + attn_out (B*T*2048 f32 = 33.6 MB)
    float* qkv  = (float*)d_ws;
    float* attn = qkv + (size_t)BATCH * SEQ * 3 * D_MODEL;

    const int M = BATCH * SEQ;   // 4096

    // 1) qkv = x @ Wqkv^T    (M=4096, N=6144, K=2048)
    gemm_bt_kernel<<<dim3(3 * D_MODEL / BN, M / BM), 256, 0, stream>>>(
        x, Wqkv, qkv, M, 3 * D_MODEL, D_MODEL);

    // 2) RoPE in place on q,k
    rope_kernel<<<dim3(BATCH * SEQ * 2 * NUM_HEADS * 64 / 256), 256, 0, stream>>>(qkv, pos);

    // 3) causal flash attention -> (B, T, H*D)
    attn_kernel<<<dim3(SEQ / TQ, BATCH * NUM_HEADS), 256, 0, stream>>>(qkv, attn);

    // 4) out = attn @ Wo^T   (M=4096, N=2048, K=2048)
    gemm_bt_kernel<<<dim3(D_MODEL / BN, M / BM), 256, 0, stream>>>(
        attn, Wo, out, M, D_MODEL, D_MODEL);
}

// Round 2
// 543.031 us; speedup vs baseline: 6.4407x; 6.4407x over previous
//
#include <hip/hip_runtime.h>
#include <math.h>
#include <stdint.h>

#define NHEADS 16
#define DK 128
#define TSEQ 2048
#define DMODEL 2048

typedef __attribute__((ext_vector_type(8))) short short8;
typedef __attribute__((ext_vector_type(4))) float floatx4;

__device__ __forceinline__ float bf2f(unsigned short h) {
    return __uint_as_float(((unsigned int)h) << 16);
}
__device__ __forceinline__ unsigned short f2bf(float f) {
    unsigned int u = __float_as_uint(f);
    u += 0x7FFFu + ((u >> 16) & 1u);
    return (unsigned short)(u >> 16);
}
__device__ __forceinline__ void async16(unsigned short* lds, const unsigned short* g) {
    __builtin_amdgcn_global_load_lds(
        (const __attribute__((address_space(1))) uint32_t*)g,
        (__attribute__((address_space(3))) uint32_t*)lds, 16, 0, 0);
}

// ===================== cast f32 -> bf16, 8 elems/thread =====================
__global__ __launch_bounds__(256) void cast_f32_to_bf16(
    const float* __restrict__ in, unsigned short* __restrict__ out, int n8)
{
    const int i = blockIdx.x * 256 + threadIdx.x;
    if (i >= n8) return;
    const float4* p4 = reinterpret_cast<const float4*>(in) + 2 * (size_t)i;
    const float4 a = p4[0], b = p4[1];
    uint32_t w0 = (uint32_t)f2bf(a.x) | ((uint32_t)f2bf(a.y) << 16);
    uint32_t w1 = (uint32_t)f2bf(a.z) | ((uint32_t)f2bf(a.w) << 16);
    uint32_t w2 = (uint32_t)f2bf(b.x) | ((uint32_t)f2bf(b.y) << 16);
    uint32_t w3 = (uint32_t)f2bf(b.z) | ((uint32_t)f2bf(b.w) << 16);
    uint4 o; o.x = w0; o.y = w1; o.z = w2; o.w = w3;
    *reinterpret_cast<uint4*>(out + 8 * (size_t)i) = o;
}

// ===================== bf16 GEMM: C[M][N] = A[M][K] @ B[N][K]^T =====================
// m97 structure: 128x128 tile, BK=32, 4 waves (2x2), each wave 64x64 = 4x4 16x16x32 MFMA frags.
template<int OUT_BF16>
__global__ __launch_bounds__(256) void gemm_bt_bf16(
    const unsigned short* __restrict__ A, const unsigned short* __restrict__ B,
    void* __restrict__ Cv, int M, int N, int K)
{
    __shared__ unsigned short As[128 * 32];
    __shared__ unsigned short Bs[128 * 32];

    const int t = threadIdx.x;
    const int lane = t & 63, w = t >> 6;
    const int row0 = blockIdx.y * 128, col0 = blockIdx.x * 128;
    const int wr = (w >> 1) * 64, wc = (w & 1) * 64;
    const int lr = lane & 15, lk = lane >> 4;

    floatx4 acc[4][4];
#pragma unroll
    for (int i = 0; i < 4; i++)
#pragma unroll
        for (int j = 0; j < 4; j++)
#pragma unroll
            for (int e = 0; e < 4; e++) acc[i][j][e] = 0.f;

    // staging chunks: 512 16B chunks per tile, 2 per lane per matrix
    const int c0 = w * 64 + lane, c1 = c0 + 256;
    const size_t ga0 = (size_t)(row0 + (c0 >> 2)) * K + ((c0 & 3) << 3);
    const size_t ga1 = (size_t)(row0 + (c1 >> 2)) * K + ((c1 & 3) << 3);
    const size_t gb0 = (size_t)(col0 + (c0 >> 2)) * K + ((c0 & 3) << 3);
    const size_t gb1 = (size_t)(col0 + (c1 >> 2)) * K + ((c1 & 3) << 3);

    for (int k0 = 0; k0 < K; k0 += 32) {
        async16(&As[c0 * 8], A + ga0 + k0);
        async16(&As[c1 * 8], A + ga1 + k0);
        async16(&Bs[c0 * 8], B + gb0 + k0);
        async16(&Bs[c1 * 8], B + gb1 + k0);
        __syncthreads();   // compiler drains vmcnt before barrier

        short8 a[4], b[4];
#pragma unroll
        for (int mi = 0; mi < 4; mi++)
            a[mi] = *(const short8*)&As[(wr + mi * 16 + lr) * 32 + lk * 8];
#pragma unroll
        for (int ni = 0; ni < 4; ni++)
            b[ni] = *(const short8*)&Bs[(wc + ni * 16 + lr) * 32 + lk * 8];
#pragma unroll
        for (int mi = 0; mi < 4; mi++)
#pragma unroll
            for (int ni = 0; ni < 4; ni++)
                acc[mi][ni] = __builtin_amdgcn_mfma_f32_16x16x32_bf16(
                    a[mi], b[ni], acc[mi][ni], 0, 0, 0);
        __syncthreads();
    }

    // C-write: D layout col = lane&15, row = (lane>>4)*4 + j  [m89-verified]
#pragma unroll
    for (int mi = 0; mi < 4; mi++)
#pragma unroll
        for (int ni = 0; ni < 4; ni++) {
            const int colb = col0 + wc + ni * 16 + lr;
#pragma unroll
            for (int j = 0; j < 4; j++) {
                const int rowb = row0 + wr + mi * 16 + lk * 4 + j;
                if (OUT_BF16)
                    ((unsigned short*)Cv)[(size_t)rowb * N + colb] = f2bf(acc[mi][ni][j]);
                else
                    ((float*)Cv)[(size_t)rowb * N + colb] = acc[mi][ni][j];
            }
        }
}

// ===================== RoPE table + apply =====================
__global__ __launch_bounds__(256) void rope_table_kernel(
    const int* __restrict__ pos, float2* __restrict__ tab)
{
    const int idx = blockIdx.x * 256 + threadIdx.x;   // 2048*64
    const int tt = idx >> 6, i = idx & 63;
    const double inv_freq = exp(-log(10000.0) * (double)i / 64.0);
    const double ang = (double)pos[tt] * inv_freq;
    tab[idx] = make_float2((float)cos(ang), (float)sin(ang));
}

__global__ __launch_bounds__(256) void rope_apply_kernel(
    unsigned short* __restrict__ qkv, const float2* __restrict__ tab)
{
    const int idx = blockIdx.x * 256 + threadIdx.x;   // B*T*2*16*64 = 8388608
    const int i  = idx & 63;
    const int h  = (idx >> 6) & 15;
    const int qk = (idx >> 10) & 1;
    const int tt = (idx >> 11) & (TSEQ - 1);
    const int b  = idx >> 22;
    const float2 cs = tab[(tt << 6) | i];
    const size_t base = (size_t)(b * TSEQ + tt) * (3 * DMODEL) + qk * DMODEL + h * DK + 2 * i;
    const uint32_t pv = *(const uint32_t*)&qkv[base];
    const float e = bf2f((unsigned short)(pv & 0xFFFF));
    const float o = bf2f((unsigned short)(pv >> 16));
    const uint32_t rv = (uint32_t)f2bf(e * cs.x - o * cs.y) |
                        ((uint32_t)f2bf(e * cs.y + o * cs.x) << 16);
    *(uint32_t*)&qkv[base] = rv;
}

// ===================== V transpose: qkvb v-part -> vt[bh][d][t] =====================
__global__ __launch_bounds__(256) void transpose_v_kernel(
    const unsigned short* __restrict__ qkvb, unsigned short* __restrict__ vt)
{
    __shared__ unsigned short tile[32][33];
    const int bh = blockIdx.z, b = bh >> 4, h = bh & 15;
    const int t0 = blockIdx.x * 32, d0 = blockIdx.y * 32;
    const int tx = threadIdx.x & 31, ty = threadIdx.x >> 5;
#pragma unroll
    for (int k = 0; k < 32; k += 8) {
        const int tt = t0 + ty + k;
        tile[ty + k][tx] = qkvb[(size_t)(b * TSEQ + tt) * (3 * DMODEL) + 2 * DMODEL + h * DK + d0 + tx];
    }
    __syncthreads();
#pragma unroll
    for (int k = 0; k < 32; k += 8) {
        const int d = d0 + ty + k;
        vt[(size_t)(bh * DK + d) * TSEQ + t0 + tx] = tile[tx][ty + k];
    }
}

// ===================== MFMA flash attention =====================
// 4 waves x 16 q-rows (QBLK=64), KVBLK=32. K rows swizzled (chunk ^= row&7),
// Vt rows padded to 40 shorts (80B, stride-5 in 16B units -> ~2-way banks).
__global__ __launch_bounds__(256) void attn_mfma_kernel(
    const unsigned short* __restrict__ qkvb, const unsigned short* __restrict__ vt,
    unsigned short* __restrict__ outb)
{
    __shared__ unsigned short Qs[64 * 128];
    __shared__ unsigned short Ks[32 * 128];
    __shared__ unsigned short Vts[128 * 40];
    __shared__ unsigned short Ps[4][16 * 40];

    const int t = threadIdx.x;
    const int lane = t & 63, w = t >> 6;
    const int lr = lane & 15, lk = lane >> 4;
    const int bh = blockIdx.y, b = bh >> 4, h = bh & 15;
    const int q0 = blockIdx.x * 64;
    const float scale = 0.08838834764831845f;   // 1/sqrt(128)

    // stage Q tile (rows 256B = 16 chunks, swizzled)
#pragma unroll
    for (int f = t; f < 64 * 16; f += 256) {
        const int r = f >> 4, c = f & 15;
        const short8 v = *(const short8*)&qkvb[(size_t)(b * TSEQ + q0 + r) * (3 * DMODEL) + h * DK + c * 8];
        *(short8*)&Qs[r * 128 + ((c ^ (r & 7)) * 8)] = v;
    }
    __syncthreads();

    // Q A-fragments: rows w*16 + lr, k = ks*32 + lk*8 .. +7
    short8 qf[4];
    {
        const int qr = w * 16 + lr;
#pragma unroll
        for (int ks = 0; ks < 4; ks++)
            qf[ks] = *(const short8*)&Qs[qr * 128 + (((ks * 4 + lk) ^ (qr & 7)) * 8)];
    }

    floatx4 accO[8];
#pragma unroll
    for (int i = 0; i < 8; i++)
#pragma unroll
        for (int j = 0; j < 4; j++) accO[i][j] = 0.f;
    float mrun[4] = {-1e30f, -1e30f, -1e30f, -1e30f};
    float lrun[4] = {0.f, 0.f, 0.f, 0.f};

    const int kv_end = q0 + 64;
    const int wmax = q0 + w * 16 + 15;   // max q-row of this wave

    for (int kv0 = 0; kv0 < kv_end; kv0 += 32) {
        // stage K tile (swizzled rows)
#pragma unroll
        for (int f = t; f < 32 * 16; f += 256) {
            const int r = f >> 4, c = f & 15;
            const short8 v = *(const short8*)&qkvb[(size_t)(b * TSEQ + kv0 + r) * (3 * DMODEL) + DMODEL + h * DK + c * 8];
            *(short8*)&Ks[r * 128 + ((c ^ (r & 7)) * 8)] = v;
        }
        // stage Vt tile: 128 d-rows x 32 kv, padded rows of 40
#pragma unroll
        for (int f = t; f < 128 * 4; f += 256) {
            const int d = f >> 2, c = f & 3;
            const short8 v = *(const short8*)&vt[(size_t)(bh * DK + d) * TSEQ + kv0 + c * 8];
            *(short8*)&Vts[d * 40 + c * 8] = v;
        }
        __syncthreads();

        if (kv0 <= wmax) {
            // QK^T: S[16q][32kv], 2 n-tiles x 4 k-slices
            floatx4 s[2];
#pragma unroll
            for (int nt = 0; nt < 2; nt++) {
#pragma unroll
                for (int j = 0; j < 4; j++) s[nt][j] = 0.f;
                const int krow = nt * 16 + lr;
#pragma unroll
                for (int ks = 0; ks < 4; ks++) {
                    const short8 kf = *(const short8*)&Ks[krow * 128 + (((ks * 4 + lk) ^ (krow & 7)) * 8)];
                    s[nt] = __builtin_amdgcn_mfma_f32_16x16x32_bf16(qf[ks], kf, s[nt], 0, 0, 0);
                }
            }
            // scale + causal mask + online softmax (wave-parallel over 16-lane groups)
            float alpha[4];
#pragma unroll
            for (int j = 0; j < 4; j++) {
                const int qrow = q0 + w * 16 + lk * 4 + j;
                float s0 = s[0][j] * scale;
                float s1 = s[1][j] * scale;
                if (kv0 + lr > qrow)      s0 = -1e30f;
                if (kv0 + 16 + lr > qrow) s1 = -1e30f;
                float mx = fmaxf(s0, s1);
#pragma unroll
                for (int off = 1; off < 16; off <<= 1) mx = fmaxf(mx, __shfl_xor(mx, off, 64));
                const float mnew = fmaxf(mrun[j], mx);
                alpha[j] = __expf(mrun[j] - mnew);
                mrun[j] = mnew;
                const float p0 = __expf(s0 - mnew);
                const float p1 = __expf(s1 - mnew);
                float ps = p0 + p1;
#pragma unroll
                for (int off = 1; off < 16; off <<= 1) ps += __shfl_xor(ps, off, 64);
                lrun[j] = lrun[j] * alpha[j] + ps;
                // P -> per-wave LDS (A-fragment relayout)
                Ps[w][(lk * 4 + j) * 40 + lr]      = f2bf(p0);
                Ps[w][(lk * 4 + j) * 40 + 16 + lr] = f2bf(p1);
            }
            // rescale O
#pragma unroll
            for (int i = 0; i < 8; i++)
#pragma unroll
                for (int j = 0; j < 4; j++) accO[i][j] *= alpha[j];
            // PV: A = P[16q][32kv], B = V[32kv][128d] (from Vt rows)
            const short8 pf = *(const short8*)&Ps[w][lr * 40 + lk * 8];
#pragma unroll
            for (int nt8 = 0; nt8 < 8; nt8++) {
                const short8 vf = *(const short8*)&Vts[(nt8 * 16 + lr) * 40 + lk * 8];
                accO[nt8] = __builtin_amdgcn_mfma_f32_16x16x32_bf16(pf, vf, accO[nt8], 0, 0, 0);
            }
        }
        __syncthreads();
    }

    // epilogue: O / l -> bf16, layout (B,T,H*DK)
#pragma unroll
    for (int j = 0; j < 4; j++) {
        const float linv = 1.f / lrun[j];
        const size_t rowoff = (size_t)(b * TSEQ + q0 + w * 16 + lk * 4 + j) * DMODEL + h * DK;
#pragma unroll
        for (int nt8 = 0; nt8 < 8; nt8++)
            outb[rowoff + nt8 * 16 + lr] = f2bf(accO[nt8][j] * linv);
    }
}

// ===================== launch =====================
extern "C" void kernel_launch(void* const* d_in, const int* in_sizes, int n_in,
                              void* d_out, int out_size, void* d_ws, size_t ws_size,
                              hipStream_t stream)
{
    const float* x    = (const float*)d_in[0];
    const int*   pos  = (const int*)d_in[1];
    const float* Wqkv = (const float*)d_in[2];
    const float* Wo   = (const float*)d_in[3];
    float* out = (float*)d_out;

    // ws layout (ushort elems): qkvb 25165824 | vt 8388608 | xb/attnb 8388608 |
    //                            wqkvb 12582912 | wob 4194304 | tab (float2) 131072
    unsigned short* qkvb  = (unsigned short*)d_ws;
    unsigned short* vtb   = qkvb + (size_t)25165824;
    unsigned short* xb    = vtb + (size_t)8388608;
    unsigned short* attnb = xb;                         // alias: xb dead after GEMM1
    unsigned short* wqkvb = xb + (size_t)8388608;
    unsigned short* wob   = wqkvb + (size_t)12582912;
    float2* tab = (float2*)(wob + (size_t)4194304);

    const int M = 2 * TSEQ;   // 4096

    cast_f32_to_bf16<<<4096, 256, 0, stream>>>(x, xb, 1048576);
    cast_f32_to_bf16<<<6144, 256, 0, stream>>>(Wqkv, wqkvb, 1572864);
    cast_f32_to_bf16<<<2048, 256, 0, stream>>>(Wo, wob, 524288);
    rope_table_kernel<<<512, 256, 0, stream>>>(pos, tab);

    // qkvb = xb @ wqkvb^T  (4096 x 6144 x 2048)
    gemm_bt_bf16<1><<<dim3(48, 32), 256, 0, stream>>>(xb, wqkvb, (void*)qkvb, M, 3 * DMODEL, DMODEL);

    rope_apply_kernel<<<32768, 256, 0, stream>>>(qkvb, tab);
    transpose_v_kernel<<<dim3(64, 4, 32), 256, 0, stream>>>(qkvb, vtb);

    attn_mfma_kernel<<<dim3(32, 32), 256, 0, stream>>>(qkvb, vtb, attnb);

    // out = attnb @ wob^T  (4096 x 2048 x 2048), fp32 out
    gemm_bt_bf16<0><<<dim3(16, 32), 256, 0, stream>>>(attnb, wob, (void*)out, M, DMODEL, DMODEL);
}

// Round 3
// 363.353 us; speedup vs baseline: 9.6257x; 1.4945x over previous
//
#include <hip/hip_runtime.h>
#include <math.h>
#include <stdint.h>

#define NHEADS 16
#define DK 128
#define TSEQ 2048
#define DMODEL 2048

typedef __attribute__((ext_vector_type(8))) short short8;
typedef __attribute__((ext_vector_type(4))) float floatx4;

__device__ __forceinline__ float bf2f(unsigned short h) {
    return __uint_as_float(((unsigned int)h) << 16);
}
__device__ __forceinline__ unsigned short f2bf(float f) {
    unsigned int u = __float_as_uint(f);
    u += 0x7FFFu + ((u >> 16) & 1u);
    return (unsigned short)(u >> 16);
}
__device__ __forceinline__ void async16(unsigned short* lds, const unsigned short* g) {
    __builtin_amdgcn_global_load_lds(
        (const __attribute__((address_space(1))) uint32_t*)g,
        (__attribute__((address_space(3))) uint32_t*)lds, 16, 0, 0);
}

// ===================== cast f32 -> bf16, 8 elems/thread =====================
__global__ __launch_bounds__(256) void cast_f32_to_bf16(
    const float* __restrict__ in, unsigned short* __restrict__ out, int n8)
{
    const int i = blockIdx.x * 256 + threadIdx.x;
    if (i >= n8) return;
    const float4* p4 = reinterpret_cast<const float4*>(in) + 2 * (size_t)i;
    const float4 a = p4[0], b = p4[1];
    uint32_t w0 = (uint32_t)f2bf(a.x) | ((uint32_t)f2bf(a.y) << 16);
    uint32_t w1 = (uint32_t)f2bf(a.z) | ((uint32_t)f2bf(a.w) << 16);
    uint32_t w2 = (uint32_t)f2bf(b.x) | ((uint32_t)f2bf(b.y) << 16);
    uint32_t w3 = (uint32_t)f2bf(b.z) | ((uint32_t)f2bf(b.w) << 16);
    uint4 o; o.x = w0; o.y = w1; o.z = w2; o.w = w3;
    *reinterpret_cast<uint4*>(out + 8 * (size_t)i) = o;
}

// ===================== bf16 GEMM: C[M][N] = A[M][K] @ B[N][K]^T =====================
template<int OUT_BF16>
__global__ __launch_bounds__(256) void gemm_bt_bf16(
    const unsigned short* __restrict__ A, const unsigned short* __restrict__ B,
    void* __restrict__ Cv, int M, int N, int K)
{
    __shared__ unsigned short As[128 * 32];
    __shared__ unsigned short Bs[128 * 32];

    const int t = threadIdx.x;
    const int lane = t & 63, w = t >> 6;
    const int row0 = blockIdx.y * 128, col0 = blockIdx.x * 128;
    const int wr = (w >> 1) * 64, wc = (w & 1) * 64;
    const int lr = lane & 15, lk = lane >> 4;

    floatx4 acc[4][4];
#pragma unroll
    for (int i = 0; i < 4; i++)
#pragma unroll
        for (int j = 0; j < 4; j++)
#pragma unroll
            for (int e = 0; e < 4; e++) acc[i][j][e] = 0.f;

    const int c0 = w * 64 + lane, c1 = c0 + 256;
    const size_t ga0 = (size_t)(row0 + (c0 >> 2)) * K + ((c0 & 3) << 3);
    const size_t ga1 = (size_t)(row0 + (c1 >> 2)) * K + ((c1 & 3) << 3);
    const size_t gb0 = (size_t)(col0 + (c0 >> 2)) * K + ((c0 & 3) << 3);
    const size_t gb1 = (size_t)(col0 + (c1 >> 2)) * K + ((c1 & 3) << 3);

    for (int k0 = 0; k0 < K; k0 += 32) {
        async16(&As[c0 * 8], A + ga0 + k0);
        async16(&As[c1 * 8], A + ga1 + k0);
        async16(&Bs[c0 * 8], B + gb0 + k0);
        async16(&Bs[c1 * 8], B + gb1 + k0);
        __syncthreads();

        short8 a[4], b[4];
#pragma unroll
        for (int mi = 0; mi < 4; mi++)
            a[mi] = *(const short8*)&As[(wr + mi * 16 + lr) * 32 + lk * 8];
#pragma unroll
        for (int ni = 0; ni < 4; ni++)
            b[ni] = *(const short8*)&Bs[(wc + ni * 16 + lr) * 32 + lk * 8];
#pragma unroll
        for (int mi = 0; mi < 4; mi++)
#pragma unroll
            for (int ni = 0; ni < 4; ni++)
                acc[mi][ni] = __builtin_amdgcn_mfma_f32_16x16x32_bf16(
                    a[mi], b[ni], acc[mi][ni], 0, 0, 0);
        __syncthreads();
    }

#pragma unroll
    for (int mi = 0; mi < 4; mi++)
#pragma unroll
        for (int ni = 0; ni < 4; ni++) {
            const int colb = col0 + wc + ni * 16 + lr;
#pragma unroll
            for (int j = 0; j < 4; j++) {
                const int rowb = row0 + wr + mi * 16 + lk * 4 + j;
                if (OUT_BF16)
                    ((unsigned short*)Cv)[(size_t)rowb * N + colb] = f2bf(acc[mi][ni][j]);
                else
                    ((float*)Cv)[(size_t)rowb * N + colb] = acc[mi][ni][j];
            }
        }
}

// ===================== RoPE table + apply =====================
__global__ __launch_bounds__(256) void rope_table_kernel(
    const int* __restrict__ pos, float2* __restrict__ tab)
{
    const int idx = blockIdx.x * 256 + threadIdx.x;   // 2048*64
    const int tt = idx >> 6, i = idx & 63;
    const double inv_freq = exp(-log(10000.0) * (double)i / 64.0);
    const double ang = (double)pos[tt] * inv_freq;
    tab[idx] = make_float2((float)cos(ang), (float)sin(ang));
}

__global__ __launch_bounds__(256) void rope_apply_kernel(
    unsigned short* __restrict__ qkv, const float2* __restrict__ tab)
{
    const int idx = blockIdx.x * 256 + threadIdx.x;   // B*T*2*16*64 = 8388608
    const int i  = idx & 63;
    const int h  = (idx >> 6) & 15;
    const int qk = (idx >> 10) & 1;
    const int tt = (idx >> 11) & (TSEQ - 1);
    const int b  = idx >> 22;
    const float2 cs = tab[(tt << 6) | i];
    const size_t base = (size_t)(b * TSEQ + tt) * (3 * DMODEL) + qk * DMODEL + h * DK + 2 * i;
    const uint32_t pv = *(const uint32_t*)&qkv[base];
    const float e = bf2f((unsigned short)(pv & 0xFFFF));
    const float o = bf2f((unsigned short)(pv >> 16));
    const uint32_t rv = (uint32_t)f2bf(e * cs.x - o * cs.y) |
                        ((uint32_t)f2bf(e * cs.y + o * cs.x) << 16);
    *(uint32_t*)&qkv[base] = rv;
}

// ===================== V transpose: qkvb v-part -> vt[bh][d][t] =====================
__global__ __launch_bounds__(256) void transpose_v_kernel(
    const unsigned short* __restrict__ qkvb, unsigned short* __restrict__ vt)
{
    __shared__ unsigned short tile[32][33];
    const int bh = blockIdx.z, b = bh >> 4, h = bh & 15;
    const int t0 = blockIdx.x * 32, d0 = blockIdx.y * 32;
    const int tx = threadIdx.x & 31, ty = threadIdx.x >> 5;
#pragma unroll
    for (int k = 0; k < 32; k += 8) {
        const int tt = t0 + ty + k;
        tile[ty + k][tx] = qkvb[(size_t)(b * TSEQ + tt) * (3 * DMODEL) + 2 * DMODEL + h * DK + d0 + tx];
    }
    __syncthreads();
#pragma unroll
    for (int k = 0; k < 32; k += 8) {
        const int d = d0 + ty + k;
        vt[(size_t)(bh * DK + d) * TSEQ + t0 + tx] = tile[tx][ty + k];
    }
}

// ===================== MFMA flash attention v3 =====================
// 4 waves x 32 q-rows (QBLK=128), KVBLK=64. Swapped QK^T (S^T = mfma(K,Q)):
// lane owns q-col => lane-local softmax. K double-buffered, V single-buffered,
// both chunk-XOR-swizzled via pre-swizzled global_load_lds source (m173).
// P relayout through per-wave LDS. Defer-max THR=8. LDS = 64KB -> 2 blocks/CU.
__global__ __launch_bounds__(256, 2) void attn_mfma2_kernel(
    const unsigned short* __restrict__ qkvb, const unsigned short* __restrict__ vt,
    unsigned short* __restrict__ outb)
{
    __shared__ unsigned short Ks[2][64 * 128];   // [buf][kv][d]    32 KB
    __shared__ unsigned short Vs[128 * 64];      // [d][kv]         16 KB
    __shared__ unsigned short Ps[4][32 * 64];    // [wave][q][kv]   16 KB

    const int t = threadIdx.x;
    const int lane = t & 63, w = t >> 6;
    const int lr = lane & 15, hi = lane >> 4;
    const int bh = blockIdx.y, b = bh >> 4, h = bh & 15;
    const int qc = (int)gridDim.x - 1 - (int)blockIdx.x;   // heavy blocks dispatch first
    const int q0 = qc * 128;
    const int q0w = q0 + w * 32;
    const float scale = 0.08838834764831845f;   // 1/sqrt(128)
    const size_t QROW = 3 * DMODEL;

    const unsigned short* kg = qkvb + (size_t)b * TSEQ * QROW + DMODEL + h * DK;
    const unsigned short* vg = vt + (size_t)bh * DK * TSEQ;

    // ---- Q fragments direct to registers (B-operand layout), pre-scaled ----
    short8 qf[2][4];
    {
        const unsigned short* qbase = qkvb + (size_t)(b * TSEQ + q0w) * QROW + h * DK;
#pragma unroll
        for (int nt = 0; nt < 2; nt++)
#pragma unroll
            for (int ks = 0; ks < 4; ks++) {
                short8 raw = *(const short8*)(qbase + (size_t)(nt * 16 + lr) * QROW + ks * 32 + hi * 8);
                short8 sc;
#pragma unroll
                for (int e = 0; e < 8; e++)
                    sc[e] = (short)f2bf(bf2f((unsigned short)raw[e]) * scale);
                qf[nt][ks] = sc;
            }
    }

    auto stageK = [&](int bufi, int kv0s) {
#pragma unroll
        for (int i = 0; i < 4; i++) {
            const int s = i * 256 + t;
            const int r = s >> 4;
            const int cc = (s & 15) ^ (r & 7);
            async16(&Ks[bufi][s * 8], kg + (size_t)(kv0s + r) * QROW + cc * 8);
        }
    };
    auto stageV = [&](int kv0s) {
#pragma unroll
        for (int i = 0; i < 4; i++) {
            const int s = i * 256 + t;
            const int r = s >> 3;
            const int cc = (s & 7) ^ (r & 7);
            async16(&Vs[s * 8], vg + (size_t)r * TSEQ + kv0s + cc * 8);
        }
    };

    floatx4 accO[2][8];
#pragma unroll
    for (int nt = 0; nt < 2; nt++)
#pragma unroll
        for (int dt = 0; dt < 8; dt++)
#pragma unroll
            for (int e = 0; e < 4; e++) accO[nt][dt][e] = 0.f;
    float mrun[2] = {-1e30f, -1e30f};
    float lrun[2] = {0.f, 0.f};

    const int ntiles = (q0 + 128) / 64;
    int kbuf = 0;

    stageK(0, 0);
    __syncthreads();

    for (int ti = 0; ti < ntiles; ti++) {
        const int kv0 = ti * 64;
        stageV(kv0);
        if (ti + 1 < ntiles) stageK(kbuf ^ 1, kv0 + 64);

        const bool active = (kv0 <= q0w + 31);
        float al[2] = {1.f, 1.f};

        if (active) {
            // ---- QK^T: S^T[kv][q] = K @ Q^T ----
            floatx4 st[4][2];
#pragma unroll
            for (int mt = 0; mt < 4; mt++)
#pragma unroll
                for (int nt = 0; nt < 2; nt++)
#pragma unroll
                    for (int e = 0; e < 4; e++) st[mt][nt][e] = 0.f;
#pragma unroll
            for (int mt = 0; mt < 4; mt++) {
                const int r = mt * 16 + lr;
#pragma unroll
                for (int ks = 0; ks < 4; ks++) {
                    const int ch = (ks * 4 + hi) ^ (r & 7);
                    const short8 kf = *(const short8*)&Ks[kbuf][(r * 16 + ch) * 8];
                    st[mt][0] = __builtin_amdgcn_mfma_f32_16x16x32_bf16(kf, qf[0][ks], st[mt][0], 0, 0, 0);
                    st[mt][1] = __builtin_amdgcn_mfma_f32_16x16x32_bf16(kf, qf[1][ks], st[mt][1], 0, 0, 0);
                }
            }
            // ---- causal mask (only on wave-diagonal tiles) ----
            if (kv0 + 63 > q0w) {
#pragma unroll
                for (int nt = 0; nt < 2; nt++) {
                    const int qg = q0w + nt * 16 + lr;
#pragma unroll
                    for (int mt = 0; mt < 4; mt++)
#pragma unroll
                        for (int rg = 0; rg < 4; rg++) {
                            const int kvg = kv0 + mt * 16 + hi * 4 + rg;
                            if (kvg > qg) st[mt][nt][rg] = -1e30f;
                        }
                }
            }
            // ---- lane-local online softmax (q-col per lane, 4-lane group reduce) ----
            float pm[2];
#pragma unroll
            for (int nt = 0; nt < 2; nt++) {
                float m = -1e30f;
#pragma unroll
                for (int mt = 0; mt < 4; mt++)
#pragma unroll
                    for (int rg = 0; rg < 4; rg++) m = fmaxf(m, st[mt][nt][rg]);
                m = fmaxf(m, __shfl_xor(m, 16, 64));
                m = fmaxf(m, __shfl_xor(m, 32, 64));
                pm[nt] = m;
            }
            if (__any((pm[0] > mrun[0] + 8.f) || (pm[1] > mrun[1] + 8.f))) {
#pragma unroll
                for (int nt = 0; nt < 2; nt++) {
                    const float mn = fmaxf(mrun[nt], pm[nt]);
                    al[nt] = __expf(mrun[nt] - mn);
                    mrun[nt] = mn;
                }
                // broadcast alpha to O-row layout and rescale
#pragma unroll
                for (int rg = 0; rg < 4; rg++) {
                    const float a0 = __shfl(al[0], hi * 4 + rg, 64);
                    const float a1 = __shfl(al[1], hi * 4 + rg, 64);
#pragma unroll
                    for (int dt = 0; dt < 8; dt++) {
                        accO[0][dt][rg] *= a0;
                        accO[1][dt][rg] *= a1;
                    }
                }
            }
            // ---- exp, row-sum, P -> per-wave LDS (A-fragment relayout) ----
#pragma unroll
            for (int nt = 0; nt < 2; nt++) {
                float ls = 0.f;
#pragma unroll
                for (int mt = 0; mt < 4; mt++)
#pragma unroll
                    for (int rg = 0; rg < 4; rg++) {
                        const float p = __expf(st[mt][nt][rg] - mrun[nt]);
                        ls += p;
                        Ps[w][(nt * 16 + lr) * 64 + mt * 16 + hi * 4 + rg] = f2bf(p);
                    }
                ls += __shfl_xor(ls, 16, 64);
                ls += __shfl_xor(ls, 32, 64);
                lrun[nt] = lrun[nt] * al[nt] + ls;
            }
        }
        __syncthreads();   // V staged; K prefetch landed; Ps visible (same-wave anyway)

        if (active) {
            // ---- PV: O[q][d] += P @ V ----
#pragma unroll
            for (int ks2 = 0; ks2 < 2; ks2++) {
                const short8 pa0 = *(const short8*)&Ps[w][(0 * 16 + lr) * 64 + ks2 * 32 + hi * 8];
                const short8 pa1 = *(const short8*)&Ps[w][(1 * 16 + lr) * 64 + ks2 * 32 + hi * 8];
#pragma unroll
                for (int dt = 0; dt < 8; dt++) {
                    const int r = dt * 16 + lr;
                    const int ch = (ks2 * 4 + hi) ^ (r & 7);
                    const short8 vf = *(const short8*)&Vs[(r * 8 + ch) * 8];
                    accO[0][dt] = __builtin_amdgcn_mfma_f32_16x16x32_bf16(pa0, vf, accO[0][dt], 0, 0, 0);
                    accO[1][dt] = __builtin_amdgcn_mfma_f32_16x16x32_bf16(pa1, vf, accO[1][dt], 0, 0, 0);
                }
            }
        }
        __syncthreads();   // PV done before next stageV overwrites Vs
        kbuf ^= 1;
    }

    // ---- epilogue: O / l -> bf16 ----
#pragma unroll
    for (int nt = 0; nt < 2; nt++) {
        const float lv_own = 1.f / lrun[nt];
#pragma unroll
        for (int rg = 0; rg < 4; rg++) {
            const float lv = __shfl(lv_own, hi * 4 + rg, 64);
            unsigned short* orow = outb + (size_t)(b * TSEQ + q0w + nt * 16 + hi * 4 + rg) * DMODEL + h * DK;
#pragma unroll
            for (int dt = 0; dt < 8; dt++)
                orow[dt * 16 + lr] = f2bf(accO[nt][dt][rg] * lv);
        }
    }
}

// ===================== launch =====================
extern "C" void kernel_launch(void* const* d_in, const int* in_sizes, int n_in,
                              void* d_out, int out_size, void* d_ws, size_t ws_size,
                              hipStream_t stream)
{
    const float* x    = (const float*)d_in[0];
    const int*   pos  = (const int*)d_in[1];
    const float* Wqkv = (const float*)d_in[2];
    const float* Wo   = (const float*)d_in[3];
    float* out = (float*)d_out;

    unsigned short* qkvb  = (unsigned short*)d_ws;
    unsigned short* vtb   = qkvb + (size_t)25165824;
    unsigned short* xb    = vtb + (size_t)8388608;
    unsigned short* attnb = xb;                         // alias: xb dead after GEMM1
    unsigned short* wqkvb = xb + (size_t)8388608;
    unsigned short* wob   = wqkvb + (size_t)12582912;
    float2* tab = (float2*)(wob + (size_t)4194304);

    const int M = 2 * TSEQ;   // 4096

    cast_f32_to_bf16<<<4096, 256, 0, stream>>>(x, xb, 1048576);
    cast_f32_to_bf16<<<6144, 256, 0, stream>>>(Wqkv, wqkvb, 1572864);
    cast_f32_to_bf16<<<2048, 256, 0, stream>>>(Wo, wob, 524288);
    rope_table_kernel<<<512, 256, 0, stream>>>(pos, tab);

    gemm_bt_bf16<1><<<dim3(48, 32), 256, 0, stream>>>(xb, wqkvb, (void*)qkvb, M, 3 * DMODEL, DMODEL);

    rope_apply_kernel<<<32768, 256, 0, stream>>>(qkvb, tab);
    transpose_v_kernel<<<dim3(64, 4, 32), 256, 0, stream>>>(qkvb, vtb);

    attn_mfma2_kernel<<<dim3(16, 32), 256, 0, stream>>>(qkvb, vtb, attnb);

    gemm_bt_bf16<0><<<dim3(16, 32), 256, 0, stream>>>(attnb, wob, (void*)out, M, DMODEL, DMODEL);
}